// Round 6
// baseline (328.083 us; speedup 1.0000x reference)
//
#include <hip/hip_runtime.h>
#include <hip/hip_bf16.h>
#include <math.h>

#define Hdim 768
#define Idim 3072
#define Tn   1024
#define En   8

using v4f    = __attribute__((ext_vector_type(4))) float;
using short8 = __attribute__((ext_vector_type(8))) short;
using short4v= __attribute__((ext_vector_type(4))) short;

__device__ inline unsigned short f2bf(float f) {
    unsigned u = __float_as_uint(f);
    u += 0x7fffu + ((u >> 16) & 1u);   // RNE
    return (unsigned short)(u >> 16);
}
__device__ inline short4v pack4(float4 v) {
    return short4v{ (short)f2bf(v.x), (short)f2bf(v.y), (short)f2bf(v.z), (short)f2bf(v.w) };
}
__device__ inline short8 pack8(float4 a, float4 b) {
    return short8{ (short)f2bf(a.x), (short)f2bf(a.y), (short)f2bf(a.z), (short)f2bf(a.w),
                   (short)f2bf(b.x), (short)f2bf(b.y), (short)f2bf(b.z), (short)f2bf(b.w) };
}

// ---------------- gate ----------------
__global__ __launch_bounds__(256) void gate_kernel(
    const float* __restrict__ x, const float* __restrict__ gw, const float* __restrict__ gb,
    float* __restrict__ gsum, float* __restrict__ gsumsq,
    int* __restrict__ count, int* __restrict__ sel)
{
    __shared__ float gws[8 * 772];
    __shared__ float lg[8][8];
    int tid = threadIdx.x;
    long t0 = (long)blockIdx.x * 8;
    for (int i = tid; i < 8 * 768; i += 256) gws[(i / 768) * 772 + (i % 768)] = gw[i];
    __syncthreads();

    int tok = tid >> 5, e = (tid >> 2) & 7, qr = tid & 3;
    const float4* xp = (const float4*)(x + (t0 + tok) * Hdim) + qr * 48;
    const float4* gp = (const float4*)(gws + e * 772) + qr * 48;
    float a0 = 0.f, a1 = 0.f;
#pragma unroll 8
    for (int i = 0; i < 48; i += 2) {
        float4 xa = xp[i], ga = gp[i], xc = xp[i + 1], gc = gp[i + 1];
        a0 += xa.x * ga.x + xa.y * ga.y + xa.z * ga.z + xa.w * ga.w;
        a1 += xc.x * gc.x + xc.y * gc.y + xc.z * gc.z + xc.w * gc.w;
    }
    float acc = a0 + a1;
    acc += __shfl_xor(acc, 1);
    acc += __shfl_xor(acc, 2);
    if (qr == 0) lg[tok][e] = acc + gb[e];
    __syncthreads();

    if (tid < 8) {
        float best = lg[tid][0]; int bi = 0;
        for (int j = 1; j < 8; j++) { float v = lg[tid][j]; if (v > best) { best = v; bi = j; } }
        sel[t0 + tid] = bi;
        atomicAdd(&count[bi], 1);
    } else if (tid < 16) {
        int e2 = tid - 8;
        float s = 0.f, ss = 0.f;
        for (int t2 = 0; t2 < 8; t2++) { float v = lg[t2][e2]; s += v; ss += v * v; }
        atomicAdd(&gsum[e2], s);
        atomicAdd(&gsumsq[e2], ss);
    }
}

// ---------------- finalize + scatter ----------------
__global__ __launch_bounds__(1024) void finscat_kernel(
    const float* __restrict__ gsum, const float* __restrict__ gsumsq,
    const int* __restrict__ count, int* __restrict__ offsets,
    const int* __restrict__ sel, int* __restrict__ perm,
    float* __restrict__ out_lb)
{
    __shared__ int lcur[8];
    int tid = threadIdx.x;
    if (tid == 0) {
        float accr = 0.f;
        for (int e = 0; e < 8; e++) {
            float mean = gsum[e] * (1.0f / 1024.0f);
            float var  = (gsumsq[e] - gsum[e] * mean) * (1.0f / 1023.0f);  // ddof=1
            accr += var / (mean * mean + 1e-8f);
        }
        out_lb[0] = 0.01f * accr * 0.125f;
        int off = 0;
        for (int e = 0; e < 8; e++) { offsets[e] = off; lcur[e] = off; off += count[e]; }
    }
    __syncthreads();
    int e = sel[tid];
    int pos = atomicAdd(&lcur[e], 1);
    perm[pos] = tid;
}

// ---------------- gather x -> bf16, bucket order ----------------
__global__ __launch_bounds__(256) void gather_x_kernel(const float* __restrict__ x,
                                                       const int* __restrict__ perm,
                                                       unsigned short* __restrict__ xb)
{
    int slot = blockIdx.x * 4 + (threadIdx.x >> 6);
    int lane = threadIdx.x & 63;
    int t = perm[slot];
    const float4* src = (const float4*)(x + (long)t * Hdim);
    unsigned short* dst = xb + (long)slot * Hdim;
#pragma unroll
    for (int i = 0; i < 3; i++) {
        int c = lane + 64 * i;
        *(short4v*)(dst + c * 4) = pack4(src[c]);
    }
}

// ==================== barrier-free register-fragment GEMMs ====================
// Wave tile 32(M)x32(N); block = 2 waves stacked on M (64 rows). No LDS, no
// __syncthreads: depth-2 software pipeline keeps global loads in flight with
// compiler-emitted fine-grained vmcnt. blockIdx.x = expert -> XCD L2 affinity.

// GEMM1: hmid = gelu(xb @ w1^T + b1), K=768 (24 steps), grid (8, 96, 3)
__global__ __launch_bounds__(128) void gemm1_kernel(
    const unsigned short* __restrict__ xb, const float* __restrict__ w1,
    const float* __restrict__ b1,
    const int* __restrict__ count, const int* __restrict__ offsets,
    unsigned short* __restrict__ hmid)
{
    int e = blockIdx.x;
    int nloc = count[e];
    int m0 = blockIdx.z << 6;
    if (m0 >= nloc) return;
    int n0 = blockIdx.y << 5;
    int off = offsets[e];

    int tid = threadIdx.x;
    int lane = tid & 63, wave = tid >> 6;
    int quad = lane >> 4, l16 = lane & 15;
    int wm = wave << 5;

    const short8* aBase[2];
#pragma unroll
    for (int i = 0; i < 2; i++) {
        int m = m0 + wm + i * 16 + l16;
        int mm = m < nloc ? m : nloc - 1;
        aBase[i] = (const short8*)(xb + (long)(off + mm) * Hdim + quad * 8);
    }
    const float4* bBase[2];
#pragma unroll
    for (int j = 0; j < 2; j++) {
        int n = n0 + j * 16 + l16;
        bBase[j] = (const float4*)(w1 + ((long)e * Idim + n) * Hdim + quad * 8);
    }

    v4f acc[2][2];
#pragma unroll
    for (int i = 0; i < 2; i++)
#pragma unroll
        for (int j = 0; j < 2; j++) acc[i][j] = (v4f){0.f, 0.f, 0.f, 0.f};

    short8 aB[3][2];
    float4 bB[3][2][2];
#define G1_LOAD(buf, ks)  {                                              \
    _Pragma("unroll") for (int i = 0; i < 2; i++)                        \
        aB[buf][i] = *(const short8*)((const unsigned short*)aBase[i] + (ks) * 32); \
    _Pragma("unroll") for (int j = 0; j < 2; j++) {                      \
        bB[buf][j][0] = *(const float4*)((const float*)bBase[j] + (ks) * 32);       \
        bB[buf][j][1] = *(const float4*)((const float*)bBase[j] + (ks) * 32 + 4);   \
    } }

    G1_LOAD(0, 0)
    G1_LOAD(1, 1)
#pragma unroll 3
    for (int ks = 0; ks < 24; ks++) {
        int c = ks % 3, p = (ks + 2) % 3;
        if (ks + 2 < 24) G1_LOAD(p, ks + 2)
        short8 bf[2];
#pragma unroll
        for (int j = 0; j < 2; j++) bf[j] = pack8(bB[c][j][0], bB[c][j][1]);
#pragma unroll
        for (int i = 0; i < 2; i++)
#pragma unroll
            for (int j = 0; j < 2; j++)
                acc[i][j] = __builtin_amdgcn_mfma_f32_16x16x32_bf16(aB[c][i], bf[j], acc[i][j], 0, 0, 0);
    }
#undef G1_LOAD

#pragma unroll
    for (int i = 0; i < 2; i++) {
        int mr = m0 + wm + i * 16 + quad * 4;
#pragma unroll
        for (int r = 0; r < 4; r++) {
            int m = mr + r;
            if (m >= nloc) continue;
            long slot = off + m;
#pragma unroll
            for (int j = 0; j < 2; j++) {
                int n = n0 + j * 16 + l16;
                float v = acc[i][j][r] + b1[e * Idim + n];
                float g = 0.5f * v * (1.0f + erff(v * 0.70710678118654752f));
                hmid[slot * Idim + n] = f2bf(g);
            }
        }
    }
}

// GEMM2: out[t] = hmid @ w2^T + b2, K=3072 (96 steps), grid (8, 24, 3), no atomics
__global__ __launch_bounds__(128) void gemm2_kernel(
    const unsigned short* __restrict__ hmid, const float* __restrict__ w2,
    const float* __restrict__ b2,
    const int* __restrict__ count, const int* __restrict__ offsets,
    const int* __restrict__ perm, float* __restrict__ out)
{
    int e = blockIdx.x;
    int nloc = count[e];
    int m0 = blockIdx.z << 6;
    if (m0 >= nloc) return;
    int n0 = blockIdx.y << 5;
    int off = offsets[e];

    int tid = threadIdx.x;
    int lane = tid & 63, wave = tid >> 6;
    int quad = lane >> 4, l16 = lane & 15;
    int wm = wave << 5;

    const short8* aBase[2];
#pragma unroll
    for (int i = 0; i < 2; i++) {
        int m = m0 + wm + i * 16 + l16;
        int mm = m < nloc ? m : nloc - 1;
        aBase[i] = (const short8*)(hmid + (long)(off + mm) * Idim + quad * 8);
    }
    const float4* bBase[2];
#pragma unroll
    for (int j = 0; j < 2; j++) {
        int n = n0 + j * 16 + l16;
        bBase[j] = (const float4*)(w2 + ((long)e * Hdim + n) * Idim + quad * 8);
    }

    v4f acc[2][2];
#pragma unroll
    for (int i = 0; i < 2; i++)
#pragma unroll
        for (int j = 0; j < 2; j++) acc[i][j] = (v4f){0.f, 0.f, 0.f, 0.f};

    short8 aB[3][2];
    float4 bB[3][2][2];
#define G2_LOAD(buf, ks)  {                                              \
    _Pragma("unroll") for (int i = 0; i < 2; i++)                        \
        aB[buf][i] = *(const short8*)((const unsigned short*)aBase[i] + (ks) * 32); \
    _Pragma("unroll") for (int j = 0; j < 2; j++) {                      \
        bB[buf][j][0] = *(const float4*)((const float*)bBase[j] + (ks) * 32);       \
        bB[buf][j][1] = *(const float4*)((const float*)bBase[j] + (ks) * 32 + 4);   \
    } }

    G2_LOAD(0, 0)
    G2_LOAD(1, 1)
#pragma unroll 3
    for (int ks = 0; ks < 96; ks++) {
        int c = ks % 3, p = (ks + 2) % 3;
        if (ks + 2 < 96) G2_LOAD(p, ks + 2)
        short8 bf[2];
#pragma unroll
        for (int j = 0; j < 2; j++) bf[j] = pack8(bB[c][j][0], bB[c][j][1]);
#pragma unroll
        for (int i = 0; i < 2; i++)
#pragma unroll
            for (int j = 0; j < 2; j++)
                acc[i][j] = __builtin_amdgcn_mfma_f32_16x16x32_bf16(aB[c][i], bf[j], acc[i][j], 0, 0, 0);
    }
#undef G2_LOAD

#pragma unroll
    for (int i = 0; i < 2; i++) {
        int mr = m0 + wm + i * 16 + quad * 4;
#pragma unroll
        for (int r = 0; r < 4; r++) {
            int m = mr + r;
            if (m >= nloc) continue;
            int t = perm[off + m];
#pragma unroll
            for (int j = 0; j < 2; j++) {
                int n = n0 + j * 16 + l16;
                out[(long)t * Hdim + n] = acc[i][j][r] + b2[e * Hdim + n];
            }
        }
    }
}

extern "C" void kernel_launch(void* const* d_in, const int* in_sizes, int n_in,
                              void* d_out, int out_size, void* d_ws, size_t ws_size,
                              hipStream_t stream)
{
    const float* x  = (const float*)d_in[0];
    const float* gw = (const float*)d_in[1];
    const float* gb = (const float*)d_in[2];
    const float* w1 = (const float*)d_in[3];
    const float* b1 = (const float*)d_in[4];
    const float* w2 = (const float*)d_in[5];
    const float* b2 = (const float*)d_in[6];
    float* out = (float*)d_out;

    float* gsum    = (float*)d_ws;
    float* gsumsq  = gsum + 8;
    int*   count   = (int*)d_ws + 16;
    int*   offsets = (int*)d_ws + 24;
    int*   sel     = (int*)d_ws + 40;
    int*   perm    = (int*)d_ws + 40 + 1024;
    unsigned short* xb   = (unsigned short*)((char*)d_ws + 8704);
    unsigned short* hmid = (unsigned short*)((char*)d_ws + 8704 + (size_t)Tn * Hdim * 2);

    hipMemsetAsync(d_ws, 0, 160, stream);
    gate_kernel<<<128, 256, 0, stream>>>(x, gw, gb, gsum, gsumsq, count, sel);
    finscat_kernel<<<1, 1024, 0, stream>>>(gsum, gsumsq, count, offsets, sel, perm,
                                           out + (long)Tn * Hdim);
    gather_x_kernel<<<256, 256, 0, stream>>>(x, perm, xb);
    gemm1_kernel<<<dim3(8, 96, 3), 128, 0, stream>>>(xb, w1, b1, count, offsets, hmid);
    gemm2_kernel<<<dim3(8, 24, 3), 128, 0, stream>>>(hmid, w2, b2, count, offsets, perm, out);
}